// Round 14
// baseline (3017.305 us; speedup 1.0000x reference)
//
#include <hip/hip_runtime.h>
#include <math.h>
#include <string.h>

#define NTRIP 44

// ---------------- single kernarg struct: entire static structure (~26KB) ----------------
struct CompArgs {
  unsigned short pairs[NTRIP * 256];  // idx_nu | idx_1<<8  (host-extracted from MT19937)
  float cg[824];                      // CG coefficients (host polar-gauss simulation)
  int outbase[NTRIP];
  int cumP[NTRIP];
};

// ---------------- compute body (round-13 proven; NT scalar stores) ----------------
template <int LAM, int EL, int LV>
__device__ __forceinline__ void le_body3(
    const float* __restrict__ ldsA, const float* __restrict__ ldsB,
    int pr, const float* __restrict__ cgp, float* __restrict__ orow) {
  constexpr int NLt[7] = {4, 9, 11, 10, 6, 3, 1};
  constexpr int SM = NLt[LV] * 256;
  constexpr int AOFF[4] = {0, 256, 1024, 2304};
  constexpr int BOFF[4] = {0, 128, 512, 1152};
  constexpr int NA = 2 * LAM + 1;
  constexpr int NB = 2 * EL + 1;
  int inu = pr & 255;
  int i1 = pr >> 8;
  const float* ap = ldsA + AOFF[LAM] + inu * NA;
  const float* bp = ldsB + BOFF[EL] + i1 * NB;
  float a[NA];
  float b[NB];
#pragma unroll
  for (int mu = 0; mu < NA; mu++) a[mu] = ap[mu];
#pragma unroll
  for (int m = 0; m < NB; m++) b[m] = bp[m];
  float acc[2 * LV + 1];
#pragma unroll
  for (int M = 0; M <= 2 * LV; M++) acc[M] = 0.0f;
  int p = 0;
#pragma unroll
  for (int mu = 0; mu < NA; mu++) {
#pragma unroll
    for (int m = 0; m < NB; m++) {
      const int Mv = (mu - LAM) + (m - EL);
      if (Mv >= -LV && Mv <= LV) {
        acc[Mv + LV] += cgp[p] * a[mu] * b[m];
        p++;
      }
    }
  }
#pragma unroll
  for (int M = 0; M <= 2 * LV; M++)
    __builtin_nontemporal_store(acc[M], &orow[(size_t)M * SM]);
}

// ---------------- compute: 1 block = 1 sample, 512 threads = both halves ----------------
__global__ __launch_bounds__(512) void le_compute_kernel(
    const float* __restrict__ A0, const float* __restrict__ A1,
    const float* __restrict__ A2, const float* __restrict__ A3,
    const float* __restrict__ B0, const float* __restrict__ B1,
    const float* __restrict__ B2, const float* __restrict__ B3,
    CompArgs args, float* __restrict__ out) {
  __shared__ float ldsA[4096];
  __shared__ float ldsB[2048];
  const int s = blockIdx.x;       // one sample per block
  const int tid = threadIdx.x;
  const int k = tid & 255;        // feature-pair index
  const int half = tid >> 8;      // 0 / 1: the two co-resident half-sweeps

  // cooperative staging: half 0 stages A (transposed, odd strides), half 1 stages B
  if (half == 0) {
    ldsA[k] = A0[(size_t)s * 256 + k];
#pragma unroll
    for (int mu = 0; mu < 3; mu++)
      ldsA[256 + k * 3 + mu] = A1[(size_t)s * 768 + mu * 256 + k];
#pragma unroll
    for (int mu = 0; mu < 5; mu++)
      ldsA[1024 + k * 5 + mu] = A2[(size_t)s * 1280 + mu * 256 + k];
#pragma unroll
    for (int mu = 0; mu < 7; mu++)
      ldsA[2304 + k * 7 + mu] = A3[(size_t)s * 1792 + mu * 256 + k];
  } else {
    if (k < 128) {
      ldsB[k] = B0[(size_t)s * 128 + k];
#pragma unroll
      for (int m = 0; m < 3; m++)
        ldsB[128 + k * 3 + m] = B1[(size_t)s * 384 + m * 128 + k];
#pragma unroll
      for (int m = 0; m < 5; m++)
        ldsB[512 + k * 5 + m] = B2[(size_t)s * 640 + m * 128 + k];
#pragma unroll
      for (int m = 0; m < 7; m++)
        ldsB[1152 + k * 7 + m] = B3[(size_t)s * 896 + m * 128 + k];
    }
  }
  __syncthreads();

  float* outs = out + (size_t)s * 65536 + k;
#define RUN(TT, LM, ELV, LV)                                             \
  le_body3<LM, ELV, LV>(ldsA, ldsB, (int)args.pairs[(TT << 8) + k],      \
                        args.cg + args.cumP[TT], outs + args.outbase[TT]);
  // bodies in outbase-sorted order, interleaved into two balanced halves;
  // both halves run simultaneously on the same CU -> co-temporal sweep of
  // this sample's 256KB output region (lowest measured write-amp config).
  if (half == 0) {
    RUN(0, 0, 0, 0)   RUN(18, 2, 2, 0)  RUN(1, 0, 1, 1)   RUN(6, 1, 1, 1)
    RUN(15, 2, 1, 1)  RUN(23, 2, 3, 1)  RUN(38, 3, 3, 1)  RUN(7, 1, 1, 2)
    RUN(11, 1, 3, 2)  RUN(16, 2, 1, 2)  RUN(24, 2, 3, 2)  RUN(33, 3, 2, 2)
    RUN(3, 0, 3, 3)   RUN(12, 1, 3, 3)  RUN(21, 2, 2, 3)  RUN(28, 3, 0, 3)
    RUN(34, 3, 2, 3)  RUN(13, 1, 3, 4)  RUN(26, 2, 3, 4)  RUN(35, 3, 2, 4)
    RUN(27, 2, 3, 5)  RUN(42, 3, 3, 5)
  } else {
    RUN(5, 1, 1, 0)   RUN(37, 3, 3, 0)  RUN(4, 1, 0, 1)   RUN(8, 1, 2, 1)
    RUN(19, 2, 2, 1)  RUN(32, 3, 2, 1)  RUN(2, 0, 2, 2)   RUN(9, 1, 2, 2)
    RUN(14, 2, 0, 2)  RUN(20, 2, 2, 2)  RUN(29, 3, 1, 2)  RUN(39, 3, 3, 2)
    RUN(10, 1, 2, 3)  RUN(17, 2, 1, 3)  RUN(25, 2, 3, 3)  RUN(30, 3, 1, 3)
    RUN(40, 3, 3, 3)  RUN(22, 2, 2, 4)  RUN(31, 3, 1, 4)  RUN(41, 3, 3, 4)
    RUN(36, 3, 2, 5)  RUN(43, 3, 3, 6)
  }
#undef RUN
}

// ---------------- host-side exact numpy RandomState(0) simulation ----------------
static void host_twist(unsigned* st) {
  for (int i = 0; i < 227; i++) {
    unsigned y = (st[i] & 0x80000000u) | (st[i + 1] & 0x7fffffffu);
    st[i] = st[i + 397] ^ (y >> 1) ^ ((y & 1u) ? 0x9908b0dfu : 0u);
  }
  for (int i = 227; i < 623; i++) {
    unsigned y = (st[i] & 0x80000000u) | (st[i + 1] & 0x7fffffffu);
    st[i] = st[i - 227] ^ (y >> 1) ^ ((y & 1u) ? 0x9908b0dfu : 0u);
  }
  unsigned y = (st[623] & 0x80000000u) | (st[0] & 0x7fffffffu);
  st[623] = st[396] ^ (y >> 1) ^ ((y & 1u) ? 0x9908b0dfu : 0u);
}

extern "C" void kernel_launch(void* const* d_in, const int* in_sizes, int n_in,
                              void* d_out, int out_size, void* d_ws, size_t ws_size,
                              hipStream_t stream) {
  const float* A0 = (const float*)d_in[0];
  const float* A1 = (const float*)d_in[1];
  const float* A2 = (const float*)d_in[2];
  const float* A3 = (const float*)d_in[3];
  const float* B0 = (const float*)d_in[4];
  const float* B1 = (const float*)d_in[5];
  const float* B2 = (const float*)d_in[6];
  const float* B3 = (const float*)d_in[7];
  float* out = (float*)d_out;

  static CompArgs cargs;  // large; deterministic recompute each call (no state carried)

  // --- static metadata (mirrors reference build_structure loops) ---
  int Pt[NTRIP];
  int nL[7] = {0, 0, 0, 0, 0, 0, 0};
  for (int lam = 0; lam <= 3; lam++)
    for (int l = 0; l <= 3; l++)
      for (int L = (lam > l ? lam - l : l - lam); L <= lam + l; L++) nL[L]++;
  int Lbase[8];
  Lbase[0] = 0;
  for (int L = 0; L < 7; L++) Lbase[L + 1] = Lbase[L] + (2 * L + 1) * nL[L] * 256;
  int bcnt[7] = {0, 0, 0, 0, 0, 0, 0};
  int t = 0, cum = 0;
  for (int lam = 0; lam <= 3; lam++)
    for (int l = 0; l <= 3; l++)
      for (int L = (lam > l ? lam - l : l - lam); L <= lam + l; L++) {
        cargs.outbase[t] = Lbase[L] + bcnt[L] * 256;
        bcnt[L]++;
        int P = 0;
        for (int mu = 0; mu <= 2 * lam; mu++)
          for (int m = 0; m <= 2 * l; m++) {
            int Mv = (mu - lam) + (m - l);
            if (Mv >= -L && Mv <= L) P++;
          }
        Pt[t] = P;
        cargs.cumP[t] = cum;
        cum += P;
        t++;
      }

  // --- exact MT19937(seed=0): randint values + legacy polar gaussians ---
  {
    unsigned st[624];
    unsigned s = 0u;
    for (int i = 0; i < 624; i++) {
      st[i] = s;
      s = 1812433253u * (s ^ (s >> 30)) + (unsigned)(i + 1);
    }
    int mti = 624;
    auto draw = [&]() -> unsigned {
      if (mti == 624) { host_twist(st); mti = 0; }
      unsigned z = st[mti++];
      z ^= z >> 11;
      z ^= (z << 7) & 0x9d2c5680u;
      z ^= (z << 15) & 0xefc60000u;
      z ^= z >> 18;
      return z;
    };
    double cached = 0.0;
    int has = 0, cgn = 0;
    for (int tt = 0; tt < NTRIP; tt++) {
      // legacy randint fast path: rng=255/127 -> mask==rng, never rejects
      unsigned short* pr = &cargs.pairs[tt * 256];
      for (int kk = 0; kk < 256; kk++) pr[kk] = (unsigned short)(draw() & 255u);
      for (int kk = 0; kk < 256; kk++)
        pr[kk] = (unsigned short)(pr[kk] | ((draw() & 127u) << 8));
      for (int p = 0; p < Pt[tt]; p++) {
        if (has) {
          cargs.cg[cgn++] = (float)cached;
          has = 0;
        } else {
          double x1, x2, r2;
          do {
            unsigned a1 = draw(); unsigned b1 = draw();
            unsigned a2 = draw(); unsigned b2 = draw();
            double d1 = ((double)(a1 >> 5) * 67108864.0 + (double)(b1 >> 6)) /
                        9007199254740992.0;
            double d2 = ((double)(a2 >> 5) * 67108864.0 + (double)(b2 >> 6)) /
                        9007199254740992.0;
            x1 = 2.0 * d1 - 1.0;
            x2 = 2.0 * d2 - 1.0;
            r2 = x1 * x1 + x2 * x2;
          } while (r2 >= 1.0 || r2 == 0.0);
          double f = sqrt(-2.0 * log(r2) / r2);
          cargs.cg[cgn++] = (float)(f * x2);
          cached = f * x1;
          has = 1;
        }
      }
    }
    for (int i = cgn; i < 824; i++) cargs.cg[i] = 0.0f;
  }

  le_compute_kernel<<<1024, 512, 0, stream>>>(
      A0, A1, A2, A3, B0, B1, B2, B3, cargs, out);
}

// Round 15
// 124.685 us; speedup vs baseline: 24.1995x; 24.1995x over previous
//
#include <hip/hip_runtime.h>
#include <math.h>
#include <string.h>

#define NTRIP 44

struct Meta {
  int outbase[NTRIP];
  int cumP[NTRIP];
};

// host->device staging image: packed pairs + cg (copied into d_ws each call)
struct WsImage {
  int pairs[NTRIP * 256];  // idx_nu | idx_1<<16
  float cg[824];
};

// ---------------- compute body (round-13 proven; NT scalar stores) ----------------
template <int LAM, int EL, int LV>
__device__ __forceinline__ void le_body3(
    const float* __restrict__ ldsA, const float* __restrict__ ldsB,
    int pr, const float* __restrict__ cgp, float* __restrict__ orow) {
  constexpr int NLt[7] = {4, 9, 11, 10, 6, 3, 1};
  constexpr int SM = NLt[LV] * 256;
  constexpr int AOFF[4] = {0, 256, 1024, 2304};
  constexpr int BOFF[4] = {0, 128, 512, 1152};
  constexpr int NA = 2 * LAM + 1;
  constexpr int NB = 2 * EL + 1;
  int inu = pr & 0xffff;
  int i1 = pr >> 16;
  const float* ap = ldsA + AOFF[LAM] + inu * NA;
  const float* bp = ldsB + BOFF[EL] + i1 * NB;
  float a[NA];
  float b[NB];
#pragma unroll
  for (int mu = 0; mu < NA; mu++) a[mu] = ap[mu];
#pragma unroll
  for (int m = 0; m < NB; m++) b[m] = bp[m];
  float acc[2 * LV + 1];
#pragma unroll
  for (int M = 0; M <= 2 * LV; M++) acc[M] = 0.0f;
  int p = 0;
#pragma unroll
  for (int mu = 0; mu < NA; mu++) {
#pragma unroll
    for (int m = 0; m < NB; m++) {
      const int Mv = (mu - LAM) + (m - EL);
      if (Mv >= -LV && Mv <= LV) {
        acc[Mv + LV] += cgp[p] * a[mu] * b[m];
        p++;
      }
    }
  }
#pragma unroll
  for (int M = 0; M <= 2 * LV; M++)
    __builtin_nontemporal_store(acc[M], &orow[(size_t)M * SM]);
}

// ---------------- compute: 1 block = 1 sample, 512 threads = both halves ----------------
__global__ __launch_bounds__(512) void le_compute_kernel(
    const float* __restrict__ A0, const float* __restrict__ A1,
    const float* __restrict__ A2, const float* __restrict__ A3,
    const float* __restrict__ B0, const float* __restrict__ B1,
    const float* __restrict__ B2, const float* __restrict__ B3,
    const int* __restrict__ pairs, const float* __restrict__ cg,
    Meta meta, float* __restrict__ out) {
  __shared__ float ldsA[4096];
  __shared__ float ldsB[2048];
  const int s = blockIdx.x;       // one sample per block
  const int tid = threadIdx.x;
  const int k = tid & 255;        // feature-pair index
  const int half = tid >> 8;      // 0 / 1: the two co-resident half-sweeps

  // cooperative staging: half 0 stages A (transposed, odd strides), half 1 stages B
  if (half == 0) {
    ldsA[k] = A0[(size_t)s * 256 + k];
#pragma unroll
    for (int mu = 0; mu < 3; mu++)
      ldsA[256 + k * 3 + mu] = A1[(size_t)s * 768 + mu * 256 + k];
#pragma unroll
    for (int mu = 0; mu < 5; mu++)
      ldsA[1024 + k * 5 + mu] = A2[(size_t)s * 1280 + mu * 256 + k];
#pragma unroll
    for (int mu = 0; mu < 7; mu++)
      ldsA[2304 + k * 7 + mu] = A3[(size_t)s * 1792 + mu * 256 + k];
  } else {
    if (k < 128) {
      ldsB[k] = B0[(size_t)s * 128 + k];
#pragma unroll
      for (int m = 0; m < 3; m++)
        ldsB[128 + k * 3 + m] = B1[(size_t)s * 384 + m * 128 + k];
#pragma unroll
      for (int m = 0; m < 5; m++)
        ldsB[512 + k * 5 + m] = B2[(size_t)s * 640 + m * 128 + k];
#pragma unroll
      for (int m = 0; m < 7; m++)
        ldsB[1152 + k * 7 + m] = B3[(size_t)s * 896 + m * 128 + k];
    }
  }
  __syncthreads();

  float* outs = out + (size_t)s * 65536 + k;
#define RUN(TT, LM, ELV, LV)                                      \
  le_body3<LM, ELV, LV>(ldsA, ldsB, pairs[(TT << 8) + k],         \
                        cg + meta.cumP[TT], outs + meta.outbase[TT]);
  // bodies in outbase-sorted order, interleaved into two balanced halves;
  // both halves run simultaneously on the same CU -> co-temporal sweep of
  // this sample's 256KB output region (lowest measured write-amp config).
  if (half == 0) {
    RUN(0, 0, 0, 0)   RUN(18, 2, 2, 0)  RUN(1, 0, 1, 1)   RUN(6, 1, 1, 1)
    RUN(15, 2, 1, 1)  RUN(23, 2, 3, 1)  RUN(38, 3, 3, 1)  RUN(7, 1, 1, 2)
    RUN(11, 1, 3, 2)  RUN(16, 2, 1, 2)  RUN(24, 2, 3, 2)  RUN(33, 3, 2, 2)
    RUN(3, 0, 3, 3)   RUN(12, 1, 3, 3)  RUN(21, 2, 2, 3)  RUN(28, 3, 0, 3)
    RUN(34, 3, 2, 3)  RUN(13, 1, 3, 4)  RUN(26, 2, 3, 4)  RUN(35, 3, 2, 4)
    RUN(27, 2, 3, 5)  RUN(42, 3, 3, 5)
  } else {
    RUN(5, 1, 1, 0)   RUN(37, 3, 3, 0)  RUN(4, 1, 0, 1)   RUN(8, 1, 2, 1)
    RUN(19, 2, 2, 1)  RUN(32, 3, 2, 1)  RUN(2, 0, 2, 2)   RUN(9, 1, 2, 2)
    RUN(14, 2, 0, 2)  RUN(20, 2, 2, 2)  RUN(29, 3, 1, 2)  RUN(39, 3, 3, 2)
    RUN(10, 1, 2, 3)  RUN(17, 2, 1, 3)  RUN(25, 2, 3, 3)  RUN(30, 3, 1, 3)
    RUN(40, 3, 3, 3)  RUN(22, 2, 2, 4)  RUN(31, 3, 1, 4)  RUN(41, 3, 3, 4)
    RUN(36, 3, 2, 5)  RUN(43, 3, 3, 6)
  }
#undef RUN
}

// ---------------- host-side exact numpy RandomState(0) simulation ----------------
static void host_twist(unsigned* st) {
  for (int i = 0; i < 227; i++) {
    unsigned y = (st[i] & 0x80000000u) | (st[i + 1] & 0x7fffffffu);
    st[i] = st[i + 397] ^ (y >> 1) ^ ((y & 1u) ? 0x9908b0dfu : 0u);
  }
  for (int i = 227; i < 623; i++) {
    unsigned y = (st[i] & 0x80000000u) | (st[i + 1] & 0x7fffffffu);
    st[i] = st[i - 227] ^ (y >> 1) ^ ((y & 1u) ? 0x9908b0dfu : 0u);
  }
  unsigned y = (st[623] & 0x80000000u) | (st[0] & 0x7fffffffu);
  st[623] = st[396] ^ (y >> 1) ^ ((y & 1u) ? 0x9908b0dfu : 0u);
}

extern "C" void kernel_launch(void* const* d_in, const int* in_sizes, int n_in,
                              void* d_out, int out_size, void* d_ws, size_t ws_size,
                              hipStream_t stream) {
  const float* A0 = (const float*)d_in[0];
  const float* A1 = (const float*)d_in[1];
  const float* A2 = (const float*)d_in[2];
  const float* A3 = (const float*)d_in[3];
  const float* B0 = (const float*)d_in[4];
  const float* B1 = (const float*)d_in[5];
  const float* B2 = (const float*)d_in[6];
  const float* B3 = (const float*)d_in[7];
  float* out = (float*)d_out;

  static WsImage img;  // persistent host staging (deterministic recompute each call)
  Meta meta;
  int Pt[NTRIP];

  // --- static metadata (mirrors reference build_structure loops) ---
  int nL[7] = {0, 0, 0, 0, 0, 0, 0};
  for (int lam = 0; lam <= 3; lam++)
    for (int l = 0; l <= 3; l++)
      for (int L = (lam > l ? lam - l : l - lam); L <= lam + l; L++) nL[L]++;
  int Lbase[8];
  Lbase[0] = 0;
  for (int L = 0; L < 7; L++) Lbase[L + 1] = Lbase[L] + (2 * L + 1) * nL[L] * 256;
  int bcnt[7] = {0, 0, 0, 0, 0, 0, 0};
  int t = 0, cum = 0;
  for (int lam = 0; lam <= 3; lam++)
    for (int l = 0; l <= 3; l++)
      for (int L = (lam > l ? lam - l : l - lam); L <= lam + l; L++) {
        meta.outbase[t] = Lbase[L] + bcnt[L] * 256;
        bcnt[L]++;
        int P = 0;
        for (int mu = 0; mu <= 2 * lam; mu++)
          for (int m = 0; m <= 2 * l; m++) {
            int Mv = (mu - lam) + (m - l);
            if (Mv >= -L && Mv <= L) P++;
          }
        Pt[t] = P;
        meta.cumP[t] = cum;
        cum += P;
        t++;
      }

  // --- exact MT19937(seed=0): randint values + legacy polar gaussians ---
  {
    unsigned st[624];
    unsigned s = 0u;
    for (int i = 0; i < 624; i++) {
      st[i] = s;
      s = 1812433253u * (s ^ (s >> 30)) + (unsigned)(i + 1);
    }
    int mti = 624;
    auto draw = [&]() -> unsigned {
      if (mti == 624) { host_twist(st); mti = 0; }
      unsigned z = st[mti++];
      z ^= z >> 11;
      z ^= (z << 7) & 0x9d2c5680u;
      z ^= (z << 15) & 0xefc60000u;
      z ^= z >> 18;
      return z;
    };
    double cached = 0.0;
    int has = 0, cgn = 0;
    for (int tt = 0; tt < NTRIP; tt++) {
      int* pr = &img.pairs[tt * 256];
      // legacy randint fast path: rng=255/127 -> mask==rng, never rejects
      for (int kk = 0; kk < 256; kk++) pr[kk] = (int)(draw() & 255u);
      for (int kk = 0; kk < 256; kk++) pr[kk] |= (int)((draw() & 127u) << 16);
      for (int p = 0; p < Pt[tt]; p++) {
        if (has) {
          img.cg[cgn++] = (float)cached;
          has = 0;
        } else {
          double x1, x2, r2;
          do {
            unsigned a1 = draw(); unsigned b1 = draw();
            unsigned a2 = draw(); unsigned b2 = draw();
            double d1 = ((double)(a1 >> 5) * 67108864.0 + (double)(b1 >> 6)) /
                        9007199254740992.0;
            double d2 = ((double)(a2 >> 5) * 67108864.0 + (double)(b2 >> 6)) /
                        9007199254740992.0;
            x1 = 2.0 * d1 - 1.0;
            x2 = 2.0 * d2 - 1.0;
            r2 = x1 * x1 + x2 * x2;
          } while (r2 >= 1.0 || r2 == 0.0);
          double f = sqrt(-2.0 * log(r2) / r2);
          img.cg[cgn++] = (float)(f * x2);
          cached = f * x1;
          has = 1;
        }
      }
    }
    for (int i = cgn; i < 824; i++) img.cg[i] = 0.0f;
  }

  // stage static tables into workspace (H2D memcpy node; graph-capturable)
  hipMemcpyAsync(d_ws, &img, sizeof(WsImage), hipMemcpyHostToDevice, stream);

  const int* pairs = (const int*)d_ws;
  const float* cgp = (const float*)((const char*)d_ws + sizeof(int) * NTRIP * 256);
  le_compute_kernel<<<1024, 512, 0, stream>>>(
      A0, A1, A2, A3, B0, B1, B2, B3, pairs, cgp, meta, out);
}

// Round 16
// 84.230 us; speedup vs baseline: 35.8222x; 1.4803x over previous
//
#include <hip/hip_runtime.h>
#include <math.h>
#include <string.h>

#define NTRIP 44
#define MAXROUNDS 44

typedef float f32x2 __attribute__((ext_vector_type(2)));

// ---------------- kernarg structs ----------------
struct GenArgs {
  unsigned init[624];   // seeded MT19937 state (before first twist)
  int idxoff[NTRIP];    // u32 stream offset of each triplet's randint block
  int nrounds;          // MT blocks actually needed (host-computed, <= MAXROUNDS)
};

struct CgArgs {
  float cg[824];        // all CG coefficients (host-computed, global gaussian order)
};

struct Meta {
  int outbase[NTRIP];
  int cumP[NTRIP];
};

__device__ __forceinline__ unsigned mt_tw(unsigned hi, unsigned lo) {
  unsigned y = (hi & 0x80000000u) | (lo & 0x7fffffffu);
  return (y >> 1) ^ ((y & 1u) ? 0x9908b0dfu : 0u);
}

// ---------------- device gen: double-buffered MT + pairs extract + cg dump ----------------
__global__ __launch_bounds__(256) void gen3_kernel(int* __restrict__ pairs,
                                                   float* __restrict__ cgout,
                                                   GenArgs ga, CgArgs ca) {
  __shared__ unsigned mt[2][624];
  __shared__ unsigned stream[MAXROUNDS * 624];
  const int tid = threadIdx.x;
  for (int i = tid; i < 624; i += 256) mt[0][i] = ga.init[i];
  __syncthreads();
  int cur = 0;
  for (int r = 0; r < ga.nrounds; r++) {
    unsigned* O = mt[cur];
    unsigned* N = mt[cur ^ 1];
    if (tid < 227) N[tid] = O[tid + 397] ^ mt_tw(O[tid], O[tid + 1]);
    __syncthreads();
    if (tid < 227) N[227 + tid] = N[tid] ^ mt_tw(O[227 + tid], O[228 + tid]);
    __syncthreads();
    for (int i = 454 + tid; i < 624; i += 256) {
      unsigned lo = (i == 623) ? N[0] : O[i + 1];
      N[i] = N[i - 227] ^ mt_tw(O[i], lo);
    }
    __syncthreads();
    for (int i = tid; i < 624; i += 256) {
      unsigned z = N[i];
      z ^= z >> 11;
      z ^= (z << 7) & 0x9d2c5680u;
      z ^= (z << 15) & 0xefc60000u;
      z ^= z >> 18;
      stream[r * 624 + i] = z;
    }
    cur ^= 1;
    __syncthreads();
  }
  // extract packed gather indices: idx_nu | idx_1<<16
  for (int t = 0; t < NTRIP; t++) {
    int off = ga.idxoff[t];
    pairs[(t << 8) + tid] =
        (int)(stream[off + tid] & 255u) | ((int)(stream[off + 256 + tid] & 127u) << 16);
  }
  // dump host-computed cg to global ws
  for (int i = tid; i < 824; i += 256) cgout[i] = ca.cg[i];
}

// ---------------- compute body: 2 adjacent columns per thread, f32x2 NT stores ----------------
template <int LAM, int EL, int LV>
__device__ __forceinline__ void le_body6(
    const float* __restrict__ ldsA, const float* __restrict__ ldsB,
    int pr0, int pr1, const float* __restrict__ cgp, float* __restrict__ orow) {
  constexpr int NLt[7] = {4, 9, 11, 10, 6, 3, 1};
  constexpr int SM = NLt[LV] * 256;
  constexpr int AOFF[4] = {0, 256, 1024, 2304};
  constexpr int BOFF[4] = {0, 128, 512, 1152};
  constexpr int NA = 2 * LAM + 1;
  constexpr int NB = 2 * EL + 1;
  const float* ap0 = ldsA + AOFF[LAM] + (pr0 & 0xffff) * NA;
  const float* bp0 = ldsB + BOFF[EL] + (pr0 >> 16) * NB;
  const float* ap1 = ldsA + AOFF[LAM] + (pr1 & 0xffff) * NA;
  const float* bp1 = ldsB + BOFF[EL] + (pr1 >> 16) * NB;
  float a0[NA], a1[NA], b0[NB], b1[NB];
#pragma unroll
  for (int mu = 0; mu < NA; mu++) { a0[mu] = ap0[mu]; a1[mu] = ap1[mu]; }
#pragma unroll
  for (int m = 0; m < NB; m++) { b0[m] = bp0[m]; b1[m] = bp1[m]; }
  float acc[2 * LV + 1][2];
#pragma unroll
  for (int M = 0; M <= 2 * LV; M++) { acc[M][0] = 0.0f; acc[M][1] = 0.0f; }
  int p = 0;
#pragma unroll
  for (int mu = 0; mu < NA; mu++) {
#pragma unroll
    for (int m = 0; m < NB; m++) {
      const int Mv = (mu - LAM) + (m - EL);
      if (Mv >= -LV && Mv <= LV) {
        float c = cgp[p];
        acc[Mv + LV][0] += c * a0[mu] * b0[m];
        acc[Mv + LV][1] += c * a1[mu] * b1[m];
        p++;
      }
    }
  }
#pragma unroll
  for (int M = 0; M <= 2 * LV; M++) {
    f32x2 v = {acc[M][0], acc[M][1]};
    __builtin_nontemporal_store(v, (f32x2*)(orow + (size_t)M * SM));
  }
}

// ---------------- compute: 1 block = 1 sample, 512 threads = 4 co-temporal quarters ----------------
__global__ __launch_bounds__(512) void le_compute_kernel(
    const float* __restrict__ A0, const float* __restrict__ A1,
    const float* __restrict__ A2, const float* __restrict__ A3,
    const float* __restrict__ B0, const float* __restrict__ B1,
    const float* __restrict__ B2, const float* __restrict__ B3,
    const int* __restrict__ pairs, const float* __restrict__ cg,
    Meta meta, float* __restrict__ out) {
  __shared__ float ldsA[4096];
  __shared__ float ldsB[2048];
  const int s = blockIdx.x;       // one sample per block
  const int tid = threadIdx.x;
  const int k = tid & 255;
  const int half = tid >> 8;

  // cooperative staging (identical to round 13): half 0 stages A, half 1 stages B
  if (half == 0) {
    ldsA[k] = A0[(size_t)s * 256 + k];
#pragma unroll
    for (int mu = 0; mu < 3; mu++)
      ldsA[256 + k * 3 + mu] = A1[(size_t)s * 768 + mu * 256 + k];
#pragma unroll
    for (int mu = 0; mu < 5; mu++)
      ldsA[1024 + k * 5 + mu] = A2[(size_t)s * 1280 + mu * 256 + k];
#pragma unroll
    for (int mu = 0; mu < 7; mu++)
      ldsA[2304 + k * 7 + mu] = A3[(size_t)s * 1792 + mu * 256 + k];
  } else {
    if (k < 128) {
      ldsB[k] = B0[(size_t)s * 128 + k];
#pragma unroll
      for (int m = 0; m < 3; m++)
        ldsB[128 + k * 3 + m] = B1[(size_t)s * 384 + m * 128 + k];
#pragma unroll
      for (int m = 0; m < 5; m++)
        ldsB[512 + k * 5 + m] = B2[(size_t)s * 640 + m * 128 + k];
#pragma unroll
      for (int m = 0; m < 7; m++)
        ldsB[1152 + k * 7 + m] = B3[(size_t)s * 896 + m * 128 + k];
    }
  }
  __syncthreads();

  const int q = tid >> 7;         // quarter 0..3
  const int j = tid & 127;        // column pair index: cols 2j, 2j+1
  float* outs = out + (size_t)s * 65536 + 2 * j;
#define RUN(TT, LM, ELV, LV)                                              \
  {                                                                       \
    int2 pp = ((const int2*)(pairs + (TT << 8)))[j];                      \
    le_body6<LM, ELV, LV>(ldsA, ldsB, pp.x, pp.y,                         \
                          cg + meta.cumP[TT], outs + meta.outbase[TT]);   \
  }
  // 44 outbase-sorted triplets round-robined into 4 balanced quarter-lists
  // (61/63/65/67 rows); all quarters co-temporal on one CU (round-13 condition).
  switch (q) {
    case 0:
      RUN(0, 0, 0, 0)  RUN(1, 0, 1, 1)  RUN(15, 2, 1, 1) RUN(38, 3, 3, 1)
      RUN(11, 1, 3, 2) RUN(24, 2, 3, 2) RUN(3, 0, 3, 3)  RUN(21, 2, 2, 3)
      RUN(34, 3, 2, 3) RUN(26, 2, 3, 4) RUN(27, 2, 3, 5)
      break;
    case 1:
      RUN(5, 1, 1, 0)  RUN(4, 1, 0, 1)  RUN(19, 2, 2, 1) RUN(2, 0, 2, 2)
      RUN(14, 2, 0, 2) RUN(29, 3, 1, 2) RUN(10, 1, 2, 3) RUN(25, 2, 3, 3)
      RUN(40, 3, 3, 3) RUN(31, 3, 1, 4) RUN(36, 3, 2, 5)
      break;
    case 2:
      RUN(18, 2, 2, 0) RUN(6, 1, 1, 1)  RUN(23, 2, 3, 1) RUN(7, 1, 1, 2)
      RUN(16, 2, 1, 2) RUN(33, 3, 2, 2) RUN(12, 1, 3, 3) RUN(28, 3, 0, 3)
      RUN(13, 1, 3, 4) RUN(35, 3, 2, 4) RUN(42, 3, 3, 5)
      break;
    default:
      RUN(37, 3, 3, 0) RUN(8, 1, 2, 1)  RUN(32, 3, 2, 1) RUN(9, 1, 2, 2)
      RUN(39, 3, 3, 2) RUN(20, 2, 2, 2) RUN(17, 2, 1, 3) RUN(30, 3, 1, 3)
      RUN(22, 2, 2, 4) RUN(41, 3, 3, 4) RUN(43, 3, 3, 6)
      break;
  }
#undef RUN
}

// ---------------- host-side exact numpy RandomState(0) simulation ----------------
static void host_twist(unsigned* st) {
  for (int i = 0; i < 227; i++) {
    unsigned y = (st[i] & 0x80000000u) | (st[i + 1] & 0x7fffffffu);
    st[i] = st[i + 397] ^ (y >> 1) ^ ((y & 1u) ? 0x9908b0dfu : 0u);
  }
  for (int i = 227; i < 623; i++) {
    unsigned y = (st[i] & 0x80000000u) | (st[i + 1] & 0x7fffffffu);
    st[i] = st[i - 227] ^ (y >> 1) ^ ((y & 1u) ? 0x9908b0dfu : 0u);
  }
  unsigned y = (st[623] & 0x80000000u) | (st[0] & 0x7fffffffu);
  st[623] = st[396] ^ (y >> 1) ^ ((y & 1u) ? 0x9908b0dfu : 0u);
}

extern "C" void kernel_launch(void* const* d_in, const int* in_sizes, int n_in,
                              void* d_out, int out_size, void* d_ws, size_t ws_size,
                              hipStream_t stream) {
  const float* A0 = (const float*)d_in[0];
  const float* A1 = (const float*)d_in[1];
  const float* A2 = (const float*)d_in[2];
  const float* A3 = (const float*)d_in[3];
  const float* B0 = (const float*)d_in[4];
  const float* B1 = (const float*)d_in[5];
  const float* B2 = (const float*)d_in[6];
  const float* B3 = (const float*)d_in[7];
  float* out = (float*)d_out;
  int* pairs = (int*)d_ws;                      // 44*256 packed (idx_nu | idx_1<<16)
  float* cgws = (float*)(pairs + NTRIP * 256);  // 824 floats

  // --- static metadata (mirrors reference build_structure loops) ---
  int Pt[NTRIP];
  Meta meta;
  CgArgs cargs;
  int nL[7] = {0, 0, 0, 0, 0, 0, 0};
  for (int lam = 0; lam <= 3; lam++)
    for (int l = 0; l <= 3; l++)
      for (int L = (lam > l ? lam - l : l - lam); L <= lam + l; L++) nL[L]++;
  int Lbase[8];
  Lbase[0] = 0;
  for (int L = 0; L < 7; L++) Lbase[L + 1] = Lbase[L] + (2 * L + 1) * nL[L] * 256;
  int bcnt[7] = {0, 0, 0, 0, 0, 0, 0};
  int t = 0, cum = 0;
  for (int lam = 0; lam <= 3; lam++)
    for (int l = 0; l <= 3; l++)
      for (int L = (lam > l ? lam - l : l - lam); L <= lam + l; L++) {
        meta.outbase[t] = Lbase[L] + bcnt[L] * 256;
        bcnt[L]++;
        int P = 0;
        for (int mu = 0; mu <= 2 * lam; mu++)
          for (int m = 0; m <= 2 * l; m++) {
            int Mv = (mu - lam) + (m - l);
            if (Mv >= -L && Mv <= L) P++;
          }
        Pt[t] = P;
        meta.cumP[t] = cum;
        cum += P;
        t++;
      }

  // --- exact MT19937(seed=0) + legacy polar-gauss simulation (deterministic) ---
  GenArgs gargs;
  {
    unsigned init[624];
    unsigned s = 0u;
    for (int i = 0; i < 624; i++) {
      init[i] = s;
      s = 1812433253u * (s ^ (s >> 30)) + (unsigned)(i + 1);
    }
    memcpy(gargs.init, init, sizeof(init));
    unsigned st[624];
    memcpy(st, init, sizeof(st));
    int mti = 624;
    int pos = 0;
    auto draw = [&]() -> unsigned {
      if (mti == 624) { host_twist(st); mti = 0; }
      unsigned z = st[mti++];
      z ^= z >> 11;
      z ^= (z << 7) & 0x9d2c5680u;
      z ^= (z << 15) & 0xefc60000u;
      z ^= z >> 18;
      pos++;
      return z;
    };
    double cached = 0.0;
    int has = 0, cgn = 0;
    for (int tt = 0; tt < NTRIP; tt++) {
      gargs.idxoff[tt] = pos;
      for (int i = 0; i < 512; i++) (void)draw();  // 256 randint(256) + 256 randint(128)
      for (int p = 0; p < Pt[tt]; p++) {
        if (has) {
          cargs.cg[cgn++] = (float)cached;
          has = 0;
        } else {
          double x1, x2, r2;
          do {
            unsigned a1 = draw(); unsigned b1 = draw();
            unsigned a2 = draw(); unsigned b2 = draw();
            double d1 = ((double)(a1 >> 5) * 67108864.0 + (double)(b1 >> 6)) /
                        9007199254740992.0;
            double d2 = ((double)(a2 >> 5) * 67108864.0 + (double)(b2 >> 6)) /
                        9007199254740992.0;
            x1 = 2.0 * d1 - 1.0;
            x2 = 2.0 * d2 - 1.0;
            r2 = x1 * x1 + x2 * x2;
          } while (r2 >= 1.0 || r2 == 0.0);
          double f = sqrt(-2.0 * log(r2) / r2);
          cargs.cg[cgn++] = (float)(f * x2);
          cached = f * x1;
          has = 1;
        }
      }
    }
    for (int i = cgn; i < 824; i++) cargs.cg[i] = 0.0f;
    gargs.nrounds = (pos + 623) / 624;
    if (gargs.nrounds > MAXROUNDS) gargs.nrounds = MAXROUNDS;  // never hit (~40)
  }

  gen3_kernel<<<1, 256, 0, stream>>>(pairs, cgws, gargs, cargs);
  le_compute_kernel<<<1024, 512, 0, stream>>>(
      A0, A1, A2, A3, B0, B1, B2, B3, pairs, cgws, meta, out);
}

// Round 17
// 64.168 us; speedup vs baseline: 47.0223x; 1.3127x over previous
//
#include <hip/hip_runtime.h>
#include <math.h>
#include <string.h>

#define NTRIP 44

typedef float f32x2 __attribute__((ext_vector_type(2)));

// ---------------- kernarg structs ----------------
struct PairsCg {
  unsigned short pairs[NTRIP * 256];  // idx_nu | idx_1<<8 (host-extracted MT19937)
  float cg[824];                      // CG coefficients (host polar-gauss)
};

struct Meta {
  int outbase[NTRIP];
  int cumP[NTRIP];
};

// ---------------- device gen: pure kernarg->ws copy/unpack (1 block, ~2us) ----------------
__global__ __launch_bounds__(256) void gen4_kernel(int* __restrict__ pairs,
                                                   float* __restrict__ cgout,
                                                   PairsCg pc) {
  const int tid = threadIdx.x;
  for (int i = tid; i < NTRIP * 256; i += 256) {
    unsigned v = pc.pairs[i];
    pairs[i] = (int)(v & 255u) | ((int)(v >> 8) << 16);
  }
  for (int i = tid; i < 824; i += 256) cgout[i] = pc.cg[i];
}

// ---------------- compute body: 2 adjacent columns per thread, f32x2 NT stores ----------------
template <int LAM, int EL, int LV>
__device__ __forceinline__ void le_body6(
    const float* __restrict__ ldsA, const float* __restrict__ ldsB,
    int pr0, int pr1, const float* __restrict__ cgp, float* __restrict__ orow) {
  constexpr int NLt[7] = {4, 9, 11, 10, 6, 3, 1};
  constexpr int SM = NLt[LV] * 256;
  constexpr int AOFF[4] = {0, 256, 1024, 2304};
  constexpr int BOFF[4] = {0, 128, 512, 1152};
  constexpr int NA = 2 * LAM + 1;
  constexpr int NB = 2 * EL + 1;
  const float* ap0 = ldsA + AOFF[LAM] + (pr0 & 0xffff) * NA;
  const float* bp0 = ldsB + BOFF[EL] + (pr0 >> 16) * NB;
  const float* ap1 = ldsA + AOFF[LAM] + (pr1 & 0xffff) * NA;
  const float* bp1 = ldsB + BOFF[EL] + (pr1 >> 16) * NB;
  float a0[NA], a1[NA], b0[NB], b1[NB];
#pragma unroll
  for (int mu = 0; mu < NA; mu++) { a0[mu] = ap0[mu]; a1[mu] = ap1[mu]; }
#pragma unroll
  for (int m = 0; m < NB; m++) { b0[m] = bp0[m]; b1[m] = bp1[m]; }
  float acc[2 * LV + 1][2];
#pragma unroll
  for (int M = 0; M <= 2 * LV; M++) { acc[M][0] = 0.0f; acc[M][1] = 0.0f; }
  int p = 0;
#pragma unroll
  for (int mu = 0; mu < NA; mu++) {
#pragma unroll
    for (int m = 0; m < NB; m++) {
      const int Mv = (mu - LAM) + (m - EL);
      if (Mv >= -LV && Mv <= LV) {
        float c = cgp[p];
        acc[Mv + LV][0] += c * a0[mu] * b0[m];
        acc[Mv + LV][1] += c * a1[mu] * b1[m];
        p++;
      }
    }
  }
#pragma unroll
  for (int M = 0; M <= 2 * LV; M++) {
    f32x2 v = {acc[M][0], acc[M][1]};
    __builtin_nontemporal_store(v, (f32x2*)(orow + (size_t)M * SM));
  }
}

// ---------------- compute: 1 block = 1 sample, 512 threads = 4 co-temporal quarters ----------------
__global__ __launch_bounds__(512) void le_compute_kernel(
    const float* __restrict__ A0, const float* __restrict__ A1,
    const float* __restrict__ A2, const float* __restrict__ A3,
    const float* __restrict__ B0, const float* __restrict__ B1,
    const float* __restrict__ B2, const float* __restrict__ B3,
    const int* __restrict__ pairs, const float* __restrict__ cg,
    Meta meta, float* __restrict__ out) {
  __shared__ float ldsA[4096];
  __shared__ float ldsB[2048];
  const int s = blockIdx.x;       // one sample per block
  const int tid = threadIdx.x;
  const int k = tid & 255;
  const int half = tid >> 8;

  // cooperative staging: half 0 stages A (transposed, odd strides), half 1 stages B
  if (half == 0) {
    ldsA[k] = A0[(size_t)s * 256 + k];
#pragma unroll
    for (int mu = 0; mu < 3; mu++)
      ldsA[256 + k * 3 + mu] = A1[(size_t)s * 768 + mu * 256 + k];
#pragma unroll
    for (int mu = 0; mu < 5; mu++)
      ldsA[1024 + k * 5 + mu] = A2[(size_t)s * 1280 + mu * 256 + k];
#pragma unroll
    for (int mu = 0; mu < 7; mu++)
      ldsA[2304 + k * 7 + mu] = A3[(size_t)s * 1792 + mu * 256 + k];
  } else {
    if (k < 128) {
      ldsB[k] = B0[(size_t)s * 128 + k];
#pragma unroll
      for (int m = 0; m < 3; m++)
        ldsB[128 + k * 3 + m] = B1[(size_t)s * 384 + m * 128 + k];
#pragma unroll
      for (int m = 0; m < 5; m++)
        ldsB[512 + k * 5 + m] = B2[(size_t)s * 640 + m * 128 + k];
#pragma unroll
      for (int m = 0; m < 7; m++)
        ldsB[1152 + k * 7 + m] = B3[(size_t)s * 896 + m * 128 + k];
    }
  }
  __syncthreads();

  const int q = tid >> 7;         // quarter 0..3
  const int j = tid & 127;        // column pair index: cols 2j, 2j+1
  float* outs = out + (size_t)s * 65536 + 2 * j;
#define RUN(TT, LM, ELV, LV)                                              \
  {                                                                       \
    int2 pp = ((const int2*)(pairs + (TT << 8)))[j];                      \
    le_body6<LM, ELV, LV>(ldsA, ldsB, pp.x, pp.y,                         \
                          cg + meta.cumP[TT], outs + meta.outbase[TT]);   \
  }
  // 44 outbase-sorted triplets round-robined into 4 balanced quarter-lists;
  // all quarters co-temporal on one CU (the proven low-write-amp condition).
  switch (q) {
    case 0:
      RUN(0, 0, 0, 0)  RUN(1, 0, 1, 1)  RUN(15, 2, 1, 1) RUN(38, 3, 3, 1)
      RUN(11, 1, 3, 2) RUN(24, 2, 3, 2) RUN(3, 0, 3, 3)  RUN(21, 2, 2, 3)
      RUN(34, 3, 2, 3) RUN(26, 2, 3, 4) RUN(27, 2, 3, 5)
      break;
    case 1:
      RUN(5, 1, 1, 0)  RUN(4, 1, 0, 1)  RUN(19, 2, 2, 1) RUN(2, 0, 2, 2)
      RUN(14, 2, 0, 2) RUN(29, 3, 1, 2) RUN(10, 1, 2, 3) RUN(25, 2, 3, 3)
      RUN(40, 3, 3, 3) RUN(31, 3, 1, 4) RUN(36, 3, 2, 5)
      break;
    case 2:
      RUN(18, 2, 2, 0) RUN(6, 1, 1, 1)  RUN(23, 2, 3, 1) RUN(7, 1, 1, 2)
      RUN(16, 2, 1, 2) RUN(33, 3, 2, 2) RUN(12, 1, 3, 3) RUN(28, 3, 0, 3)
      RUN(13, 1, 3, 4) RUN(35, 3, 2, 4) RUN(42, 3, 3, 5)
      break;
    default:
      RUN(37, 3, 3, 0) RUN(8, 1, 2, 1)  RUN(32, 3, 2, 1) RUN(9, 1, 2, 2)
      RUN(39, 3, 3, 2) RUN(20, 2, 2, 2) RUN(17, 2, 1, 3) RUN(30, 3, 1, 3)
      RUN(22, 2, 2, 4) RUN(41, 3, 3, 4) RUN(43, 3, 3, 6)
      break;
  }
#undef RUN
}

// ---------------- host-side exact numpy RandomState(0) simulation ----------------
static void host_twist(unsigned* st) {
  for (int i = 0; i < 227; i++) {
    unsigned y = (st[i] & 0x80000000u) | (st[i + 1] & 0x7fffffffu);
    st[i] = st[i + 397] ^ (y >> 1) ^ ((y & 1u) ? 0x9908b0dfu : 0u);
  }
  for (int i = 227; i < 623; i++) {
    unsigned y = (st[i] & 0x80000000u) | (st[i + 1] & 0x7fffffffu);
    st[i] = st[i - 227] ^ (y >> 1) ^ ((y & 1u) ? 0x9908b0dfu : 0u);
  }
  unsigned y = (st[623] & 0x80000000u) | (st[0] & 0x7fffffffu);
  st[623] = st[396] ^ (y >> 1) ^ ((y & 1u) ? 0x9908b0dfu : 0u);
}

extern "C" void kernel_launch(void* const* d_in, const int* in_sizes, int n_in,
                              void* d_out, int out_size, void* d_ws, size_t ws_size,
                              hipStream_t stream) {
  const float* A0 = (const float*)d_in[0];
  const float* A1 = (const float*)d_in[1];
  const float* A2 = (const float*)d_in[2];
  const float* A3 = (const float*)d_in[3];
  const float* B0 = (const float*)d_in[4];
  const float* B1 = (const float*)d_in[5];
  const float* B2 = (const float*)d_in[6];
  const float* B3 = (const float*)d_in[7];
  float* out = (float*)d_out;
  int* pairs = (int*)d_ws;                      // 44*256 packed (idx_nu | idx_1<<16)
  float* cgws = (float*)(pairs + NTRIP * 256);  // 824 floats

  // --- static metadata (mirrors reference build_structure loops) ---
  int Pt[NTRIP];
  Meta meta;
  static PairsCg pc;  // deterministic recompute each call
  int nL[7] = {0, 0, 0, 0, 0, 0, 0};
  for (int lam = 0; lam <= 3; lam++)
    for (int l = 0; l <= 3; l++)
      for (int L = (lam > l ? lam - l : l - lam); L <= lam + l; L++) nL[L]++;
  int Lbase[8];
  Lbase[0] = 0;
  for (int L = 0; L < 7; L++) Lbase[L + 1] = Lbase[L] + (2 * L + 1) * nL[L] * 256;
  int bcnt[7] = {0, 0, 0, 0, 0, 0, 0};
  int t = 0, cum = 0;
  for (int lam = 0; lam <= 3; lam++)
    for (int l = 0; l <= 3; l++)
      for (int L = (lam > l ? lam - l : l - lam); L <= lam + l; L++) {
        meta.outbase[t] = Lbase[L] + bcnt[L] * 256;
        bcnt[L]++;
        int P = 0;
        for (int mu = 0; mu <= 2 * lam; mu++)
          for (int m = 0; m <= 2 * l; m++) {
            int Mv = (mu - lam) + (m - l);
            if (Mv >= -L && Mv <= L) P++;
          }
        Pt[t] = P;
        meta.cumP[t] = cum;
        cum += P;
        t++;
      }

  // --- exact MT19937(seed=0): randint values + legacy polar gaussians ---
  {
    unsigned st[624];
    unsigned s = 0u;
    for (int i = 0; i < 624; i++) {
      st[i] = s;
      s = 1812433253u * (s ^ (s >> 30)) + (unsigned)(i + 1);
    }
    int mti = 624;
    auto draw = [&]() -> unsigned {
      if (mti == 624) { host_twist(st); mti = 0; }
      unsigned z = st[mti++];
      z ^= z >> 11;
      z ^= (z << 7) & 0x9d2c5680u;
      z ^= (z << 15) & 0xefc60000u;
      z ^= z >> 18;
      return z;
    };
    double cached = 0.0;
    int has = 0, cgn = 0;
    for (int tt = 0; tt < NTRIP; tt++) {
      unsigned short* pr = &pc.pairs[tt * 256];
      // legacy randint fast path: rng=255/127 -> mask==rng, never rejects
      for (int kk = 0; kk < 256; kk++) pr[kk] = (unsigned short)(draw() & 255u);
      for (int kk = 0; kk < 256; kk++)
        pr[kk] = (unsigned short)(pr[kk] | ((draw() & 127u) << 8));
      for (int p = 0; p < Pt[tt]; p++) {
        if (has) {
          pc.cg[cgn++] = (float)cached;
          has = 0;
        } else {
          double x1, x2, r2;
          do {
            unsigned a1 = draw(); unsigned b1 = draw();
            unsigned a2 = draw(); unsigned b2 = draw();
            double d1 = ((double)(a1 >> 5) * 67108864.0 + (double)(b1 >> 6)) /
                        9007199254740992.0;
            double d2 = ((double)(a2 >> 5) * 67108864.0 + (double)(b2 >> 6)) /
                        9007199254740992.0;
            x1 = 2.0 * d1 - 1.0;
            x2 = 2.0 * d2 - 1.0;
            r2 = x1 * x1 + x2 * x2;
          } while (r2 >= 1.0 || r2 == 0.0);
          double f = sqrt(-2.0 * log(r2) / r2);
          pc.cg[cgn++] = (float)(f * x2);
          cached = f * x1;
          has = 1;
        }
      }
    }
    for (int i = cgn; i < 824; i++) pc.cg[i] = 0.0f;
  }

  gen4_kernel<<<1, 256, 0, stream>>>(pairs, cgws, pc);
  le_compute_kernel<<<1024, 512, 0, stream>>>(
      A0, A1, A2, A3, B0, B1, B2, B3, pairs, cgws, meta, out);
}